// Round 11
// baseline (176.256 us; speedup 1.0000x reference)
//
#include <hip/hip_runtime.h>

#define NTOT 12288
#define GAL  4096
#define DIM  256
#define NEG_CNT 12276.0f
#define THR 1e-6f

// ws float offsets
#define SQ_OFF    0          // [12288] norms of quantized rows
#define AN_OFF    12288      // [4096]  pass-1 full row sums
#define DNEG_OFF  16384      // [4096]  (AN - possum)/12276
#define KS_OFF    20480      // [4096]  pass-2 kept sums (unmasked)
#define KC_OFF    24576      // [4096]  pass-2 kept counts
#define POSD_OFF  28672      // [4096*12] positive-pair dists
#define BF_OFF    81920      // bf16 buffer: 12288*256 ushorts

typedef __attribute__((ext_vector_type(8))) short bf16x8;
typedef __attribute__((ext_vector_type(4))) float f32x4;

template <int V> struct IC { static constexpr int value = V; };

__device__ __forceinline__ void gld16(void* lds_p, const void* g) {
    __builtin_amdgcn_global_load_lds(
        (const __attribute__((address_space(1))) unsigned int*)g,
        (__attribute__((address_space(3))) unsigned int*)lds_p, 16, 0, 0);
}

__device__ __forceinline__ float bfu_lo(unsigned u) { return __uint_as_float(u << 16); }
__device__ __forceinline__ float bfu_hi(unsigned u) { return __uint_as_float(u & 0xffff0000u); }

// ---- 1. quantize fp32 -> bf16 (RNE) + norms of quantized rows ----
__global__ __launch_bounds__(256) void prep_kernel(const float* __restrict__ in,
                                                   unsigned short* __restrict__ bf,
                                                   float* __restrict__ sq) {
    const int t = threadIdx.x;
    const int w = t >> 6, l = t & 63;
    const int row = blockIdx.x * 4 + w;
    const float4 v = *reinterpret_cast<const float4*>(&in[(size_t)row * DIM + l * 4]);
    const float vv[4] = {v.x, v.y, v.z, v.w};
    unsigned short h[4];
    float s = 0.f;
#pragma unroll
    for (int i = 0; i < 4; ++i) {
        const unsigned u = __float_as_uint(vv[i]);
        const unsigned r = (u + 0x7fffu + ((u >> 16) & 1u)) >> 16;   // RNE
        h[i] = (unsigned short)r;
        const float q = __uint_as_float(r << 16);
        s = fmaf(q, q, s);
    }
    *reinterpret_cast<ushort4*>(&bf[(size_t)row * DIM + l * 4]) =
        make_ushort4(h[0], h[1], h[2], h[3]);
#pragma unroll
    for (int o = 32; o > 0; o >>= 1) s += __shfl_xor(s, o);
    if (l == 0) sq[row] = s;
}

// ---- 2. A-stationary MFMA distance GEMM ----
// Grid 8x32 = 256 blocks (1/CU). Block: 128 gallery rows x 1536 cols.
// 256 threads = 4 waves (1/SIMD -> full 512-reg budget; R9/R10 lesson:
// 8 waves cap at 256 regs and acc[8][4] spilled). A strip staged once,
// af[4][8] in 128 VGPRs; B in 24 units of 32KB through 4 rotating buffers,
// counted vmcnt(24) = 3 units in flight. Row sums persist in registers.
template <int PASS>
__global__ __launch_bounds__(256, 1) void gemm_kernel(const unsigned short* __restrict__ bf,
                                                      const float* __restrict__ ws_ro,
                                                      float* __restrict__ ws) {
    __shared__ __align__(16) unsigned short lds[65536];  // 128 KB = 4 x 32KB bufs
    __shared__ float tab[1792];   // [0:128) sqa | [128:256) dn^2 | [256:1792) col norms
    const int t = threadIdx.x, l = t & 63, w = t >> 6;
    const int wrow = w >> 1, wcol = w & 1;               // 2x2 wave grid, 64x64 each
    const int c_base = blockIdx.x * 1536;
    const int m0 = blockIdx.y * 128;

    // table loads first (uniform instruction count across all waves!)
    const float sqa_v = ws_ro[SQ_OFF + GAL + m0 + (t & 127)];
    float dn_v = 0.f;
    if (PASS == 2) dn_v = ws_ro[DNEG_OFF + m0 + (t & 127)];
    float sqc_v[6];
#pragma unroll
    for (int i = 0; i < 6; ++i) sqc_v[i] = ws_ro[SQ_OFF + c_base + i * 256 + t];

    // stage A (128 rows x 256 K = 64 KB) into bufs 2+3 region; 4-bit XOR swizzle
    // on the SOURCE k-chunk (rule 21: linear LDS dest, swizzled global source)
#pragma unroll
    for (int i = 0; i < 16; ++i) {
        const int ci = i * 256 + t;                    // 0..4095
        const int row = ci >> 5, kd = ci & 31;
        const int kg = (kd & 16) | ((kd & 15) ^ (row & 15));
        gld16(&lds[32768 + ci * 8], &bf[(size_t)(GAL + m0 + row) * DIM + kg * 8]);
    }

    auto stageB = [&](int u) {                          // 32 KB unit: 128 cols x 128 K
        const int tt = u >> 1, hh = u & 1;
#pragma unroll
        for (int i = 0; i < 8; ++i) {
            const int ci = i * 256 + t;                // 0..2047
            const int c = ci >> 4, kd = ci & 15;
            const int kg = kd ^ (c & 15);
            gld16(&lds[(u & 3) * 16384 + ci * 8],
                  &bf[(size_t)(c_base + tt * 128 + c) * DIM + (hh * 16 + kg) * 8]);
        }
    };

    stageB(0); stageB(1);

    // tables arrived (A + B0 + B1 = 32 still in flight)
    asm volatile("s_waitcnt vmcnt(32)" ::: "memory");
    tab[t & 127] = sqa_v;                              // dup writes from t>=128: same value
    if (PASS == 2) tab[128 + (t & 127)] = dn_v * dn_v;
#pragma unroll
    for (int i = 0; i < 6; ++i) tab[256 + i * 256 + t] = sqc_v[i];

    // A arrived (B0+B1 = 16 in flight): extract af into registers
    asm volatile("s_waitcnt vmcnt(16)" ::: "memory");
    bf16x8 af[4][8];
#pragma unroll
    for (int f = 0; f < 4; ++f) {
        const int row = wrow * 64 + f * 16 + (l & 15);
#pragma unroll
        for (int ks = 0; ks < 8; ++ks) {
            const int kc = ks * 4 + (l >> 4);
            const int kd = (kc & 16) | ((kc & 15) ^ (row & 15));
            af[f][ks] = *reinterpret_cast<const bf16x8*>(&lds[32768 + row * 256 + kd * 8]);
        }
    }
    asm volatile("s_waitcnt lgkmcnt(0)" ::: "memory");
    __builtin_amdgcn_sched_barrier(0);                 // rule 18
    __builtin_amdgcn_s_barrier();                      // tabs visible, A free everywhere

    float sqa_r[16], dn2_r[16];
#pragma unroll
    for (int fi = 0; fi < 4; ++fi)
#pragma unroll
        for (int j = 0; j < 4; ++j) {
            const int rl = wrow * 64 + fi * 16 + (l >> 4) * 4 + j;
            sqa_r[fi * 4 + j] = tab[rl];
            dn2_r[fi * 4 + j] = (PASS == 2) ? tab[128 + rl] : 0.f;
        }

    stageB(2); stageB(3);                              // A region now reusable

    f32x4 acc[4][4];
    float rs[16], rc[16];
#pragma unroll
    for (int q = 0; q < 16; ++q) { rs[q] = 0.f; rc[q] = 0.f; }
#pragma unroll
    for (int fi = 0; fi < 4; ++fi)
#pragma unroll
        for (int fj = 0; fj < 4; ++fj) acc[fi][fj] = (f32x4){0.f, 0.f, 0.f, 0.f};

    // one unit = 128 cols x 128 K: 16 ds_read_b128, 64 MFMA. H static (rule 20).
    auto unit = [&](auto Nc, auto Hc, int tt) {
        constexpr int N = decltype(Nc)::value;
        constexpr int H = decltype(Hc)::value;
        asm volatile("s_waitcnt vmcnt(%0)" :: "i"(N) : "memory");  // unit data complete
        __builtin_amdgcn_s_barrier();                              // ...for ALL waves
        const unsigned short* bp = &lds[((2 * tt + H) & 3) * 16384];
#pragma unroll
        for (int ks = 0; ks < 4; ++ks) {
            bf16x8 bg[4];
#pragma unroll
            for (int fj = 0; fj < 4; ++fj) {
                const int c = wcol * 64 + fj * 16 + (l & 15);
                const int kc = ks * 4 + (l >> 4);
                bg[fj] = *reinterpret_cast<const bf16x8*>(&bp[c * 128 + (kc ^ (c & 15)) * 8]);
            }
#pragma unroll
            for (int fi = 0; fi < 4; ++fi)
#pragma unroll
                for (int fj = 0; fj < 4; ++fj)
                    acc[fi][fj] = __builtin_amdgcn_mfma_f32_16x16x32_bf16(
                        af[fi][H * 4 + ks], bg[fj], acc[fi][fj], 0, 0, 0);
        }
        if (H == 1) {                                  // tile complete: fold into row sums
            float sqb4[4];
#pragma unroll
            for (int fj = 0; fj < 4; ++fj)
                sqb4[fj] = tab[256 + tt * 128 + wcol * 64 + fj * 16 + (l & 15)];
#pragma unroll
            for (int fi = 0; fi < 4; ++fi)
#pragma unroll
                for (int fj = 0; fj < 4; ++fj) {
#pragma unroll
                    for (int j = 0; j < 4; ++j) {
                        const float d2 = fmaf(-2.f, acc[fi][fj][j], sqa_r[fi * 4 + j] + sqb4[fj]);
                        const float d = sqrtf(fmaxf(d2, 1e-12f));
                        if (PASS == 1) {
                            rs[fi * 4 + j] += d;
                        } else {
                            const bool kp = (d2 > 1e-12f) && (d2 < dn2_r[fi * 4 + j]);
                            rs[fi * 4 + j] += kp ? d : 0.f;
                            rc[fi * 4 + j] += kp ? 1.f : 0.f;
                        }
                    }
                    acc[fi][fj] = (f32x4){0.f, 0.f, 0.f, 0.f};
                }
        }
        __builtin_amdgcn_s_barrier();                  // all reads of this buf retired
        const int nu = 2 * tt + H + 4;
        if (nu < 24) stageB(nu);                       // refill the buffer just freed
    };

    for (int tt = 0; tt < 10; ++tt) {
        unit(IC<24>{}, IC<0>{}, tt);
        unit(IC<24>{}, IC<1>{}, tt);
    }
    unit(IC<24>{}, IC<0>{}, 10);
    unit(IC<16>{}, IC<1>{}, 10);
    unit(IC<8>{},  IC<0>{}, 11);
    unit(IC<0>{},  IC<1>{}, 11);

    // ---- reduce over the 16 lanes sharing (l>>4), then atomics ----
#pragma unroll
    for (int m = 1; m < 16; m <<= 1)
#pragma unroll
        for (int q = 0; q < 16; ++q) {
            rs[q] += __shfl_xor(rs[q], m);
            if (PASS == 2) rc[q] += __shfl_xor(rc[q], m);
        }
    if ((l & 15) == 0) {
#pragma unroll
        for (int fi = 0; fi < 4; ++fi)
#pragma unroll
            for (int j = 0; j < 4; ++j) {
                const int gr = m0 + wrow * 64 + fi * 16 + (l >> 4) * 4 + j;
                if (PASS == 1) {
                    atomicAdd(&ws[AN_OFF + gr], rs[fi * 4 + j]);
                } else {
                    atomicAdd(&ws[KS_OFF + gr], rs[fi * 4 + j]);
                    atomicAdd(&ws[KC_OFF + gr], rc[fi * 4 + j]);
                }
            }
    }
}

// ---- 3. positive pairs (12 per gallery row, known structurally) + dneg ----
// targets[i]==targets[j]  <=>  ((i&4095)>>2)==((j&4095)>>2)
__global__ __launch_bounds__(64) void pos_kernel(const unsigned short* __restrict__ bf,
                                                 float* __restrict__ ws) {
    const int gidx = blockIdx.x;          // gallery row 0..4095
    const int l = threadIdx.x;
    const int p = l >> 2, q4 = l & 3;     // pair index, K-quarter
    const int r = GAL + gidx;
    float dot = 0.f;
    int j = 0;
    if (p < 12) {
        const int t3 = p >> 2, q = p & 3;
        j = t3 * 4096 + ((gidx >> 2) << 2) + q;
        const unsigned short* pr = &bf[(size_t)r * DIM + q4 * 64];
        const unsigned short* pc = &bf[(size_t)j * DIM + q4 * 64];
#pragma unroll
        for (int it = 0; it < 8; ++it) {
            const uint4 ua = *reinterpret_cast<const uint4*>(&pr[it * 8]);
            const uint4 ub = *reinterpret_cast<const uint4*>(&pc[it * 8]);
            const unsigned a[4] = {ua.x, ua.y, ua.z, ua.w};
            const unsigned b[4] = {ub.x, ub.y, ub.z, ub.w};
#pragma unroll
            for (int k = 0; k < 4; ++k) {
                dot = fmaf(bfu_lo(a[k]), bfu_lo(b[k]), dot);
                dot = fmaf(bfu_hi(a[k]), bfu_hi(b[k]), dot);
            }
        }
    }
    dot += __shfl_xor(dot, 1);
    dot += __shfl_xor(dot, 2);
    __shared__ float pd[16];
    float dist = 0.f;
    if (q4 == 0) {
        if (p < 12) {
            const float d2 = ws[SQ_OFF + r] + ws[SQ_OFF + j] - 2.f * dot;
            dist = sqrtf(fmaxf(d2, 1e-12f));
            ws[POSD_OFF + gidx * 12 + p] = dist;
        }
        pd[p] = (p < 12) ? dist : 0.f;
    }
    __syncthreads();
    if (l == 0) {
        float s = 0.f;
#pragma unroll
        for (int i = 0; i < 12; ++i) s += pd[i];
        ws[DNEG_OFF + gidx] = (ws[AN_OFF + gidx] - s) * (1.f / NEG_CNT);
    }
}

// ---- 4. finish: subtract positives that slipped past the unmasked filter,
//         row means, ap mean, output scalar — one block ----
__global__ __launch_bounds__(1024) void finish_kernel(const float* __restrict__ ws,
                                                      float* __restrict__ out) {
    const int t = threadIdx.x;
    float rm = 0.f, aps = 0.f, apc = 0.f;
#pragma unroll
    for (int it = 0; it < 4; ++it) {
        const int g = it * 1024 + t;
        float ks = ws[KS_OFF + g], kc = ws[KC_OFF + g];
        const float dn = ws[DNEG_OFF + g];
#pragma unroll
        for (int p = 0; p < 12; ++p) {
            const float d = ws[POSD_OFF + g * 12 + p];
            if (d > THR) { aps += d; apc += 1.f; }
            if (d > THR && d < dn) { ks -= d; kc -= 1.f; }
        }
        rm += ks / kc;
    }
#pragma unroll
    for (int o = 1; o < 64; o <<= 1) {
        rm += __shfl_xor(rm, o); aps += __shfl_xor(aps, o); apc += __shfl_xor(apc, o);
    }
    __shared__ float s0[16], s1[16], s2[16];
    const int wv = t >> 6;
    if ((t & 63) == 0) { s0[wv] = rm; s1[wv] = aps; s2[wv] = apc; }
    __syncthreads();
    if (t == 0) {
        float R = 0.f, A = 0.f, C = 0.f;
#pragma unroll
        for (int i = 0; i < 16; ++i) { R += s0[i]; A += s1[i]; C += s2[i]; }
        const float an_mean = R / (float)GAL;
        const float ap_mean = A / C;
        out[0] = ap_mean / an_mean;
    }
}

extern "C" void kernel_launch(void* const* d_in, const int* in_sizes, int n_in,
                              void* d_out, int out_size, void* d_ws, size_t ws_size,
                              hipStream_t stream) {
    const float* in = (const float*)d_in[0];
    float* ws = (float*)d_ws;
    unsigned short* bf = (unsigned short*)(ws + BF_OFF);
    float* out = (float*)d_out;

    // zero AN/DNEG/KS/KC (atomically accumulated / derived regions)
    hipMemsetAsync((char*)d_ws + AN_OFF * sizeof(float), 0,
                   (KC_OFF + GAL - AN_OFF) * sizeof(float), stream);
    prep_kernel<<<NTOT / 4, 256, 0, stream>>>(in, bf, ws + SQ_OFF);
    dim3 grid(8, 32);
    gemm_kernel<1><<<grid, 256, 0, stream>>>(bf, ws, ws);
    pos_kernel<<<GAL, 64, 0, stream>>>(bf, ws);
    gemm_kernel<2><<<grid, 256, 0, stream>>>(bf, ws, ws);
    finish_kernel<<<1, 1024, 0, stream>>>(ws, out);
}